// Round 4
// baseline (465.814 us; speedup 1.0000x reference)
//
#include <hip/hip_runtime.h>
#include <hip/hip_bf16.h>
#include <stdint.h>

// NTM single step. Sizes fixed by the problem.
#define B_   256
#define N_   32768
#define M_   64
#define R_   4
#define U_   256
#define DIN_ 512
#define DC_  768      // Din + R*M
#define J4_  1024     // 4*U
#define Q_   1024     // R*B
#define NPART_ 64     // n-chunks for fused attention partials

typedef __attribute__((ext_vector_type(8))) short short8v;   // 8 bf16 (4 VGPRs)
typedef __attribute__((ext_vector_type(4))) float f32x4;

__device__ __forceinline__ float sigm(float x){ return 1.f/(1.f+__expf(-x)); }
__device__ __forceinline__ float tanh_f(float x){ float e=__expf(2.f*x); return 1.f - 2.f/(e+1.f); }
__device__ __forceinline__ unsigned short f2bf(float x){
    unsigned u = __float_as_uint(x);
    u += 0x7FFFu + ((u>>16)&1u);
    return (unsigned short)(u>>16);
}
__device__ __forceinline__ unsigned pack_bf2(float lo, float hi){
    return (unsigned)f2bf(lo) | ((unsigned)f2bf(hi) << 16);
}

// ---------------- zero scratch that needs zeros ----------------
__global__ __launch_bounds__(256) void k_zero(int* lflag, float* l){
    int i = blockIdx.x*256 + threadIdx.x;
    if(i < N_) lflag[i] = 0;
    if(i < Q_) l[i] = 0.f;
}

// ---------------- row norms of A + bf16 copy of A ----------------
__global__ __launch_bounds__(256) void k_anorm(const float* A, float* anorm, unsigned short* A_bf){
    int n = blockIdx.x*4 + (threadIdx.x>>6);
    int lane = threadIdx.x & 63;
    float v = A[n*64 + lane];
    A_bf[n*64 + lane] = f2bf(v);
    float s = v*v;
    #pragma unroll
    for(int m=1;m<64;m<<=1) s += __shfl_xor(s, m, 64);
    if(lane==0) anorm[n] = sqrtf(s);
}

// ---------------- per-row argmin of wu_prev ----------------
__global__ __launch_bounds__(256) void k_argmin(const float* wu, int* least, int* lflag){
    __shared__ float sv[256]; __shared__ int si[256];
    int b = blockIdx.x, t = threadIdx.x;
    const float* row = wu + (size_t)b*N_;
    float bv = 3.4e38f; int bi = 0;
    for(int n=t; n<N_; n+=256){ float v = row[n]; if(v < bv){ bv=v; bi=n; } }
    sv[t]=bv; si[t]=bi; __syncthreads();
    for(int s=128;s>0;s>>=1){
        if(t<s){
            float ov=sv[t+s]; int oi=si[t+s];
            if(ov<sv[t] || (ov==sv[t] && oi<si[t])){ sv[t]=ov; si[t]=oi; }
        }
        __syncthreads();
    }
    if(t==0){ least[b]=si[0]; lflag[si[0]]=1; }
}

// ---------------- LSTM gates GEMM (16 K-slices of 64) ----------------
__global__ __launch_bounds__(256) void k_lstm_gemm(const float* x, const float* rp, const float* h,
                                                   const float* W, const float* Uw, float* gpart){
    __shared__ float s_in[8*64];
    int bt = blockIdx.x >> 4, ks = blockIdx.x & 15;
    int b0 = bt*8, t = threadIdx.x;
    #pragma unroll
    for(int i=t; i<512; i+=256){
        int bb = i>>6, kk = i&63, b = b0+bb;
        float v;
        if(ks < 8)       v = x[b*DIN_ + ks*64 + kk];
        else if(ks < 12) v = rp[(size_t)(ks-8)*(B_*M_) + b*64 + kk];
        else             v = h[b*U_ + (ks-12)*64 + kk];
        s_in[bb*64 + kk] = v;
    }
    __syncthreads();
    float4 acc[8];
    #pragma unroll
    for(int i=0;i<8;i++) acc[i] = make_float4(0.f,0.f,0.f,0.f);
    const float* Wsel; int krel;
    if(ks < 12){ Wsel = W; krel = ks*64; } else { Wsel = Uw; krel = (ks-12)*64; }
    int j0 = t*4;
    #pragma unroll 4
    for(int kk=0; kk<64; kk++){
        float4 w = *(const float4*)(Wsel + (size_t)(krel+kk)*J4_ + j0);
        #pragma unroll
        for(int bb=0;bb<8;bb++){
            float s = s_in[bb*64 + kk];
            acc[bb].x += s*w.x; acc[bb].y += s*w.y; acc[bb].z += s*w.z; acc[bb].w += s*w.w;
        }
    }
    #pragma unroll
    for(int bb=0;bb<8;bb++)
        *(float4*)(gpart + (size_t)ks*(B_*J4_) + (size_t)(b0+bb)*J4_ + j0) = acc[bb];
}

// ---------------- LSTM activations -> h_new ----------------
__global__ __launch_bounds__(256) void k_lstm_act(const float* gpart, const float* bias, const float* c,
                                                  float* h_new, float* out){
    int b = blockIdx.x, u = threadIdx.x;
    float gi=bias[u], gf=bias[256+u], gg=bias[512+u], go=bias[768+u];
    #pragma unroll
    for(int s=0;s<16;s++){
        const float* gp = gpart + (size_t)s*(B_*J4_) + (size_t)b*J4_;
        gi += gp[u]; gf += gp[256+u]; gg += gp[512+u]; go += gp[768+u];
    }
    float cn = sigm(gf)*c[b*U_+u] + sigm(gi)*tanh_f(gg);
    float hn = sigm(go)*tanh_f(cn);
    h_new[b*U_+u] = hn;
    out[(size_t)b*512 + u] = hn;
}

// ---------------- keys kt (+bf16), knorm, alpha, aktT[r][m][b] bf16 ----------------
__global__ __launch_bounds__(64) void k_kta(const float* h_new, const float* Wk, const float* bk,
                                            const float* Wa, const float* ba,
                                            float* kt, unsigned short* kt_bf, unsigned short* aktT,
                                            float* alpha, float* knorm){
    __shared__ float h_l[256];
    int r = blockIdx.x >> 8, b = blockIdx.x & 255, m = threadIdx.x;
    for(int i=m;i<256;i+=64) h_l[i] = h_new[b*U_ + i];
    __syncthreads();
    float acc = bk[r*64 + m];
    const float* wkp = Wk + (size_t)r*U_*M_ + m;
    #pragma unroll 8
    for(int u=0;u<256;u++) acc += h_l[u] * wkp[u*64];
    float k = tanh_f(acc);
    float s = k*k;
    #pragma unroll
    for(int mm=1;mm<64;mm<<=1) s += __shfl_xor(s, mm, 64);
    float pa = 0.f;
    #pragma unroll
    for(int uu=0; uu<4; uu++){ int u = m*4+uu; pa += h_l[u]*Wa[u*R_ + r]; }
    #pragma unroll
    for(int mm=1;mm<64;mm<<=1) pa += __shfl_xor(pa, mm, 64);
    float al = sigm(tanh_f(pa + ba[r]));
    int q = r*256 + b;
    kt[q*64 + m]    = k;
    kt_bf[q*64 + m] = f2bf(k);
    aktT[(size_t)(r*64 + m)*256 + b] = f2bf(al*k);   // transposed, k(=b)-major
    if(m==0){ knorm[q] = sqrtf(s); alpha[q] = al; }
}

// ---------------- fused G-GEMM (MFMA, direct strided global loads) + scatter + tanh chain + Vt ----------------
// grid 512 = N/64. Block 256 (4 waves). Wave w computes n-sub w (16 rows) x 64 m x all 4 r.
// A-fragments: wr[b][n] read as strided scalar f32 loads (full 64B-line utilization),
// converted to bf16 in registers. B-fragments: aktT (L2-resident) direct 16B loads. No LDS
// in the main loop -> no bank conflicts, no barriers, loads pipeline freely.
__global__ __launch_bounds__(256) void k_Gfused(const float* wrp, const unsigned short* aktT,
                                                const float* A, const float* kt, const float* alpha,
                                                const int* least, const int* lflag,
                                                unsigned short* Vt){
    __shared__ __align__(16) char vstage[8192];   // [64 m][128B row] bf16, XOR-swizzled
    __shared__ int least_l[256];
    int nb = blockIdx.x*64, t = threadIdx.x;
    int w = t>>6, lane = t&63;
    int r16 = lane&15, hq = lane>>4;
    for(int i=t;i<256;i+=256) least_l[i] = least[i];

    f32x4 acc[4][4];   // [r][msub]
    #pragma unroll
    for(int r=0;r<4;r++)
        #pragma unroll
        for(int ms=0;ms<4;ms++) acc[r][ms] = (f32x4){0.f,0.f,0.f,0.f};

    int n_g = nb + w*16 + r16;           // this lane's A-operand row (global n)
    #pragma unroll 2
    for(int kt8=0; kt8<8; kt8++){
        int b0 = kt8*32;
        #pragma unroll
        for(int r=0;r<4;r++){
            // ---- A-fragment: wr[b0+hq*8+j][n_g], j=0..7 (stride-N_ scalar loads) ----
            const float* colp = wrp + ((size_t)(r*B_ + b0 + hq*8))*N_ + n_g;
            float v0 = colp[0];        float v1 = colp[(size_t)N_];
            float v2 = colp[2*(size_t)N_]; float v3 = colp[3*(size_t)N_];
            float v4 = colp[4*(size_t)N_]; float v5 = colp[5*(size_t)N_];
            float v6 = colp[6*(size_t)N_]; float v7 = colp[7*(size_t)N_];
            union { short8v s; unsigned u[4]; } af;
            af.u[0] = pack_bf2(v0,v1); af.u[1] = pack_bf2(v2,v3);
            af.u[2] = pack_bf2(v4,v5); af.u[3] = pack_bf2(v6,v7);
            // ---- B-fragments from aktT (L2-resident), 4 m-subtiles ----
            #pragma unroll
            for(int ms=0;ms<4;ms++){
                short8v bf = *(const short8v*)(aktT + ((size_t)(r*64 + ms*16 + r16))*256 + b0 + hq*8);
                acc[r][ms] = __builtin_amdgcn_mfma_f32_16x16x32_bf16(af.s, bf, acc[r][ms], 0, 0, 0);
            }
        }
    }
    __syncthreads();   // least_l ready; vstage free
    #pragma unroll
    for(int j=0;j<4;j++){
        int nl = w*16 + hq*4 + j, gn = nb + nl;
        int fl = lflag[gn];
        float er = fl ? 0.f : 1.f;
        float sadd[4][4];
        #pragma unroll
        for(int r=0;r<4;r++){ sadd[r][0]=0.f; sadd[r][1]=0.f; sadd[r][2]=0.f; sadd[r][3]=0.f; }
        if(fl){
            for(int b=0;b<256;b++){
                if(least_l[b]==gn){
                    #pragma unroll
                    for(int r=0;r<4;r++){
                        float am = 1.f - alpha[r*256+b];
                        const float* kp = kt + ((size_t)(r*256+b))*64 + r16;
                        #pragma unroll
                        for(int ms=0;ms<4;ms++) sadd[r][ms] += am * kp[ms*16];
                    }
                }
            }
        }
        #pragma unroll
        for(int ms=0;ms<4;ms++){
            int m = ms*16 + r16;
            float v = A[(size_t)gn*64 + m] * er;
            #pragma unroll
            for(int r=0;r<4;r++) v = tanh_f(v + acc[r][ms][j] + sadd[r][ms]);
            *(unsigned short*)(vstage + m*128 + ((nl*2) ^ ((m&7)<<4))) = f2bf(v);
        }
    }
    __syncthreads();
    int m = t>>2, cq = t&3;
    #pragma unroll
    for(int hh=0;hh<2;hh++){
        uint4 v = *(const uint4*)(vstage + m*128 + ((cq*32 + hh*16) ^ ((m&7)<<4)));
        *(uint4*)(Vt + (size_t)m*N_ + nb + cq*16 + hh*8) = v;
    }
}

// ---------------- fused attention: scores (MFMA) -> LDS P (bf16) -> PV (MFMA) ----------------
// grid: 1024 blocks = 64 n-parts x 16 q-tiles; block 256 = 4 waves, wave w owns 16 q rows.
__global__ __launch_bounds__(256) void k_attn(const unsigned short* kt_bf, const unsigned short* A_bf,
                                              const unsigned short* Vt, const float* knorm,
                                              const float* anorm, float* part, float* l){
    __shared__ __align__(16) unsigned short Pl[64*256];   // [64 q][256 n], XOR-swizzled
    int nc = blockIdx.x >> 4, qt = blockIdx.x & 15;
    int qb = qt*64, nb = nc*512;
    int lane = threadIdx.x & 63, w = threadIdx.x >> 6;
    int r16 = lane & 15, hq = lane >> 4;
    const short8v* kp = (const short8v*)(kt_bf + (size_t)(qb + w*16 + r16)*64 + hq*8);
    short8v ka0 = kp[0], ka1 = kp[4];
    float kn[4];
    #pragma unroll
    for(int j=0;j<4;j++) kn[j] = knorm[qb + w*16 + hq*4 + j];
    f32x4 O[4];
    #pragma unroll
    for(int mt=0;mt<4;mt++) O[mt] = (f32x4){0.f,0.f,0.f,0.f};
    float lp[4] = {0.f,0.f,0.f,0.f};
    int g2 = (r16 >> 2) & 3;

    for(int c=0; c<2; c++){
        int n0c = nb + c*256;
        __syncthreads();
        // ---- scores phase ----
        for(int nt=0; nt<16; nt++){
            int ntb = n0c + nt*16;
            const short8v* bp = (const short8v*)(A_bf + (size_t)(ntb + r16)*64 + hq*8);
            f32x4 acc = (f32x4){0.f,0.f,0.f,0.f};
            acc = __builtin_amdgcn_mfma_f32_16x16x32_bf16(ka0, bp[0], acc, 0, 0, 0);
            acc = __builtin_amdgcn_mfma_f32_16x16x32_bf16(ka1, bp[4], acc, 0, 0, 0);
            float an = anorm[ntb + r16];
            unsigned um[4];
            #pragma unroll
            for(int j=0;j<4;j++){
                float p = __expf(__fdividef(acc[j], kn[j]*an + 1e-16f));
                lp[j] += p;
                um[j] = (unsigned)f2bf(p);
            }
            int nl = nt*16 + (r16 & ~1);
            #pragma unroll
            for(int j=0;j<4;j++){
                unsigned up = __shfl_xor((int)um[j], 1, 64);
                if((lane & 1) == 0){
                    unsigned word = um[j] | (up << 16);
                    int byteoff = (w*16 + hq*4 + j)*512 + ((nl ^ (hq<<4)) << 1);
                    *(unsigned*)((char*)Pl + byteoff) = word;
                }
            }
        }
        __syncthreads();
        // ---- PV phase ----
        #pragma unroll 2
        for(int ks=0; ks<8; ks++){
            short8v pa = *(const short8v*)((const char*)Pl +
                          ((w*16 + r16)*512 + (((ks*32 + hq*8) ^ (g2<<4)) << 1)));
            #pragma unroll
            for(int mt=0; mt<4; mt++){
                const short8v* vp = (const short8v*)(Vt + (size_t)(mt*16 + r16)*N_ + n0c + ks*32 + hq*8);
                O[mt] = __builtin_amdgcn_mfma_f32_16x16x32_bf16(pa, vp[0], O[mt], 0, 0, 0);
            }
        }
    }
    #pragma unroll
    for(int mt=0; mt<4; mt++)
        #pragma unroll
        for(int j=0;j<4;j++)
            part[((size_t)nc*Q_ + (qb + w*16 + hq*4 + j))*64 + mt*16 + r16] = O[mt][j];
    #pragma unroll
    for(int j=0;j<4;j++){
        #pragma unroll
        for(int m2=1;m2<16;m2<<=1) lp[j] += __shfl_xor(lp[j], m2, 64);
        if(r16 == 0) atomicAdd(l + qb + w*16 + hq*4 + j, lp[j]);
    }
}

// ---------------- final reduce over n-parts, normalize, write reads ----------------
__global__ __launch_bounds__(256) void k_reduce(const float* part, const float* l, float* out){
    int tg = blockIdx.x*256 + threadIdx.x;   // 65536 = Q_*64
    int q = tg >> 6, m = tg & 63;
    float s = 0.f;
    #pragma unroll 8
    for(int cc=0;cc<NPART_;cc++) s += part[(size_t)cc*(Q_*64) + tg];
    float val = s / l[q];
    int r = q >> 8, b = q & 255;
    out[(size_t)b*512 + 256 + r*64 + m] = val;
}

extern "C" void kernel_launch(void* const* d_in, const int* in_sizes, int n_in,
                              void* d_out, int out_size, void* d_ws, size_t ws_size,
                              hipStream_t stream) {
    const float* x        = (const float*)d_in[0];
    const float* A        = (const float*)d_in[1];
    const float* wr_prev  = (const float*)d_in[2];
    const float* wu_prev  = (const float*)d_in[3];
    const float* read_prev= (const float*)d_in[4];
    const float* h        = (const float*)d_in[5];
    const float* c        = (const float*)d_in[6];
    const float* W        = (const float*)d_in[7];
    const float* Uw       = (const float*)d_in[8];
    const float* bvec     = (const float*)d_in[9];
    const float* Wk       = (const float*)d_in[10];
    const float* bk       = (const float*)d_in[11];
    const float* Wa       = (const float*)d_in[12];
    const float* ba       = (const float*)d_in[13];
    float* out = (float*)d_out;

    char* wsp = (char*)d_ws;
    float* gpart  = (float*)(wsp);                              // 16 MB
    float* part   = (float*)(wsp + 16777216);                   // 16 MB
    unsigned short* A_bf  = (unsigned short*)(wsp + 33554432);  // 4 MB
    unsigned short* Vt_bf = (unsigned short*)(wsp + 37748736);  // 4 MB
    unsigned short* aktT  = (unsigned short*)(wsp + 41943040);  // 128 KB
    float* kt     = (float*)(wsp + 42074112);                   // 256 KB
    unsigned short* kt_bf = (unsigned short*)(wsp + 42336256);  // 128 KB
    float* h_new  = (float*)(wsp + 42467328);                   // 256 KB
    float* alpha  = (float*)(wsp + 42729472);
    float* knorm  = (float*)(wsp + 42733568);
    float* anorm  = (float*)(wsp + 42737664);
    int*   lflag  = (int*)  (wsp + 42868736);
    float* l      = (float*)(wsp + 42999808);
    int*   least  = (int*)  (wsp + 43003904);

    k_zero     <<<128, 256, 0, stream>>>(lflag, l);
    k_anorm    <<<8192,256, 0, stream>>>(A, anorm, A_bf);
    k_argmin   <<<256, 256, 0, stream>>>(wu_prev, least, lflag);
    k_lstm_gemm<<<512, 256, 0, stream>>>(x, read_prev, h, W, Uw, gpart);
    k_lstm_act <<<256, 256, 0, stream>>>(gpart, bvec, c, h_new, out);
    k_kta      <<<1024, 64, 0, stream>>>(h_new, Wk, bk, Wa, ba, kt, kt_bf, aktT, alpha, knorm);
    k_Gfused   <<<512, 256, 0, stream>>>(wr_prev, aktT, A, kt, alpha, least, lflag, Vt_bf);
    k_attn     <<<1024,256, 0, stream>>>(kt_bf, A_bf, Vt_bf, knorm, anorm, part, l);
    k_reduce   <<<256, 256, 0, stream>>>(part, l, out);
}